// Round 11
// baseline (182.965 us; speedup 1.0000x reference)
//
#include <hip/hip_runtime.h>

#define T_TOK 32768   // B*S
#define NQ    8
#define FFN   2048
#define EMB   512
#define BM    128
#define BN    256
#define BK    32
#define NCHUNK (FFN / BK)   // 64

typedef __attribute__((ext_vector_type(8)))  short short8;
typedef __attribute__((ext_vector_type(16))) float f32x16;
typedef __attribute__((ext_vector_type(2)))  unsigned int u32x2;

__device__ __forceinline__ unsigned short f2bf(float f) {
  unsigned int u = __float_as_uint(f);
  u += 0x7fffu + ((u >> 16) & 1u);
  return (unsigned short)(u >> 16);
}

__device__ __forceinline__ unsigned pk2bf(float lo, float hi) {
#if __has_builtin(__builtin_amdgcn_cvt_pk_bf16_f32)
  typedef __attribute__((ext_vector_type(2))) __bf16 bf2;
  bf2 p = __builtin_amdgcn_cvt_pk_bf16_f32(lo, hi);
  return *(unsigned*)&p;
#else
  return (unsigned)f2bf(lo) | ((unsigned)f2bf(hi) << 16);
#endif
}

// ---------------------------------------------------------------------------
// prep_all (R10-verified):
//  (1) W2[FFN][EMB] fp32 -> w2f bf16 in MFMA B-FRAGMENT ORDER:
//      region (tile, kc) of 1024 bf16 at ((tile*NCHUNK)+kc)*1024; elem
//      i = ks*512 + lane*8 + e holds W2[k][col], col = tile*32 + (lane&31),
//      k = kc*32 + ks*16 + (lane>>5)*8 + e.
//      -> main kernel reads a frag as ONE coalesced dwordx4 (lane*16B).
//  (2) w1t16[f][16]: k<8 = W1[k][f], k==8 = b1[f] (bias row; bq gives 1.0),
//      k>8 = 0.
// ---------------------------------------------------------------------------
__global__ void prep_all(const float* __restrict__ W1,
                         const float* __restrict__ b1,
                         const float* __restrict__ W2,
                         unsigned short* __restrict__ w1t,
                         unsigned short* __restrict__ w2f) {
  __shared__ float t[32][33];
  const int kb  = blockIdx.x * 32;   // f tile (kc = blockIdx.x)
  const int nb  = blockIdx.y * 32;   // col tile
  const int tid = threadIdx.x;
  const int c = tid & 31, r0 = tid >> 5;
#pragma unroll
  for (int p = 0; p < 4; ++p)
    t[r0 + p * 8][c] = W2[(size_t)(kb + r0 + p * 8) * EMB + nb + c];
  __syncthreads();
  {
    const int ks = tid >> 7;
    const int hh = (tid >> 6) & 1;
    const int cc = (tid >> 1) & 31;
    const int e0 = (tid & 1) * 4;
    ushort4 v;
    v.x = f2bf(t[ks * 16 + hh * 8 + e0 + 0][cc]);
    v.y = f2bf(t[ks * 16 + hh * 8 + e0 + 1][cc]);
    v.z = f2bf(t[ks * 16 + hh * 8 + e0 + 2][cc]);
    v.w = f2bf(t[ks * 16 + hh * 8 + e0 + 3][cc]);
    *(ushort4*)(w2f + (size_t)(blockIdx.y * NCHUNK + blockIdx.x) * 1024 +
                tid * 4) = v;
  }
  if (blockIdx.x == 0) {
    const int f     = blockIdx.y * 128 + (tid >> 1);
    const int khalf = tid & 1;
    unsigned short v8[8];
#pragma unroll
    for (int j = 0; j < 8; ++j) {
      const int k = khalf * 8 + j;
      float val = (k < 8) ? W1[(size_t)k * FFN + f]
                          : (k == 8 ? b1[f] : 0.f);
      v8[j] = f2bf(val);
    }
    *(uint4*)(w1t + (size_t)f * 16 + khalf * 8) = *(uint4*)v8;
  }
}

// ---------------------------------------------------------------------------
// Fused main, R13: ZERO-LDS register-streamed w2 (R10 idea x R11 geometry).
//   R12 falsified the convoy theory at 2 blocks/CU; R11's period accounting
//   shows the LDS pipe is the largest consumer (192 KiB/period/CU ~= 1536
//   cyc, 49% > MFMA's 37%) because every wave re-reads the whole shared
//   buffer. Fix: drop LDS/barriers entirely; B-frags stream global->VGPR
//   from the frag-ordered w2f (coalesced dwordx4, L1/L2-resident).
//   R10's version of this died at launch_bounds(256,4): 64 VGPR = no
//   prefetch window -> serialized L2 round trips. Here (256,2) gives 256
//   VGPR: 8-frag windows (32 regs each), gemm1(nc) covers ks0 latency,
//   8 ks0-MFMAs cover ks1 latency. acc 128 + windows 64 + af 16 + addrs
//   ~16 + bq 4 + temporaries ~= 240.
//   Spill tripwires: VGPR <= 256, WRITE_SIZE exactly 65536 KB.
// ---------------------------------------------------------------------------
__global__ __launch_bounds__(256, 2) void ffq_main(
    const float* __restrict__ x,
    const float* __restrict__ theta,
    const unsigned short* __restrict__ w1t,
    const unsigned short* __restrict__ w2f,
    const float* __restrict__ b2,
    float* __restrict__ out) {

  const int tid  = threadIdx.x;
  const int wave = tid >> 6;
  const int lane = tid & 63;
  const int nl   = lane & 31;
  const int hi   = lane >> 5;
  const int tok0 = blockIdx.x * BM;
  const int nt0  = blockIdx.y * 8;   // first of 8 col-tiles (BN=256)

  // ---- bq: B[k=q][tok]; hi half selects the bias row (k=8 -> 1.0) ----
  float cth[8];
  {
    const float4* tp = (const float4*)theta;
    float4 t0 = tp[0], t1 = tp[1];
    cth[0] = __cosf(t0.x); cth[1] = __cosf(t0.y);
    cth[2] = __cosf(t0.z); cth[3] = __cosf(t0.w);
    cth[4] = __cosf(t1.x); cth[5] = __cosf(t1.y);
    cth[6] = __cosf(t1.z); cth[7] = __cosf(t1.w);
  }
  short8 bq;
  {
    const float4* xp =
        (const float4*)(x + (size_t)(tok0 + wave * 32 + nl) * NQ);
    float4 x0 = xp[0], x1 = xp[1];
    float q0 = __cosf(x0.x) * cth[0], q1 = __cosf(x0.y) * cth[1];
    float q2 = __cosf(x0.z) * cth[2], q3 = __cosf(x0.w) * cth[3];
    float q4 = __cosf(x1.x) * cth[4], q5 = __cosf(x1.y) * cth[5];
    float q6 = __cosf(x1.z) * cth[6], q7 = __cosf(x1.w) * cth[7];
    uint4 uu;
    uu.x = pk2bf(q0, q1); uu.y = pk2bf(q2, q3);
    uu.z = pk2bf(q4, q5); uu.w = pk2bf(q6, q7);
    if (hi) { uu.x = 0x00003f80u; uu.y = 0; uu.z = 0; uu.w = 0; }  // k=8: 1.0
    bq = *(short8*)&uu;
  }

  // ---- per-col-tile frag base pointers (frag(kc,ks) at +kc*1024+ks*512) --
  const unsigned short* w2fl = w2f + (size_t)lane * 8;
  const unsigned short* p0 = w2fl + (size_t)(nt0 + 0) * NCHUNK * 1024;
  const unsigned short* p1 = w2fl + (size_t)(nt0 + 1) * NCHUNK * 1024;
  const unsigned short* p2 = w2fl + (size_t)(nt0 + 2) * NCHUNK * 1024;
  const unsigned short* p3 = w2fl + (size_t)(nt0 + 3) * NCHUNK * 1024;
  const unsigned short* p4 = w2fl + (size_t)(nt0 + 4) * NCHUNK * 1024;
  const unsigned short* p5 = w2fl + (size_t)(nt0 + 5) * NCHUNK * 1024;
  const unsigned short* p6 = w2fl + (size_t)(nt0 + 6) * NCHUNK * 1024;
  const unsigned short* p7 = w2fl + (size_t)(nt0 + 7) * NCHUNK * 1024;

  f32x16 acc[8];
#pragma unroll
  for (int nt = 0; nt < 8; ++nt)
#pragma unroll
    for (int r = 0; r < 16; ++r) acc[nt][r] = 0.f;

  // ---- GEMM1 -> A-frags (R7/R10/R11-verified permlane routing) ----
  auto gemm1 = [&](short8 aw, short8& oA, short8& oB) {
    f32x16 c1;
#pragma unroll
    for (int r = 0; r < 16; ++r) c1[r] = 0.f;
    c1 = __builtin_amdgcn_mfma_f32_32x32x16_bf16(aw, bq, c1, 0, 0, 0);
    unsigned Q[8];
#pragma unroll
    for (int p = 0; p < 8; ++p) {
      float lo = c1[2 * p]     > 0.f ? c1[2 * p]     : 0.f;
      float hl = c1[2 * p + 1] > 0.f ? c1[2 * p + 1] : 0.f;
      Q[p] = pk2bf(lo, hl);
    }
    u32x2 s0 = __builtin_amdgcn_permlane32_swap(Q[0], Q[2], false, false);
    u32x2 s1 = __builtin_amdgcn_permlane32_swap(Q[1], Q[3], false, false);
    u32x2 s2 = __builtin_amdgcn_permlane32_swap(Q[4], Q[6], false, false);
    u32x2 s3 = __builtin_amdgcn_permlane32_swap(Q[5], Q[7], false, false);
    uint4 uA; uA.x = s0[0]; uA.y = s1[0]; uA.z = s0[1]; uA.w = s1[1];
    uint4 uB; uB.x = s2[0]; uB.y = s3[0]; uB.z = s2[1]; uB.w = s3[1];
    oA = *(short8*)&uA;
    oB = *(short8*)&uB;
  };

  // ---- prologue: gemm1(chunk 0) ----
  short8 afA_c, afB_c, afA_n, afB_n;
  {
    short8 aw0 = *(const short8*)(w1t + (size_t)nl * 16 + hi * 8);
    gemm1(aw0, afA_c, afB_c);
  }

#pragma unroll 2
  for (int kc = 0; kc < NCHUNK; ++kc) {
    const int nc = (kc + 1 < NCHUNK) ? kc + 1 : NCHUNK - 1;  // clamp: uniform
    const int kb = kc * 1024;                                // frag offset

    // ---- ks=0 frag window (8 coalesced dwordx4 from L1/L2) ----
    short8 b00 = *(const short8*)(p0 + kb);
    short8 b10 = *(const short8*)(p1 + kb);
    short8 b20 = *(const short8*)(p2 + kb);
    short8 b30 = *(const short8*)(p3 + kb);
    short8 b40 = *(const short8*)(p4 + kb);
    short8 b50 = *(const short8*)(p5 + kb);
    short8 b60 = *(const short8*)(p6 + kb);
    short8 b70 = *(const short8*)(p7 + kb);

    // ---- GEMM1(nc): independent VALU/MFMA chain covers ks0 latency ----
    {
      short8 aw =
          *(const short8*)(w1t + (size_t)(nc * BK + nl) * 16 + hi * 8);
      gemm1(aw, afA_n, afB_n);
    }

    // ---- ks=1 frag window (issued before ks0 MFMAs; covered by them) ----
    short8 b01 = *(const short8*)(p0 + kb + 512);
    short8 b11 = *(const short8*)(p1 + kb + 512);
    short8 b21 = *(const short8*)(p2 + kb + 512);
    short8 b31 = *(const short8*)(p3 + kb + 512);
    short8 b41 = *(const short8*)(p4 + kb + 512);
    short8 b51 = *(const short8*)(p5 + kb + 512);
    short8 b61 = *(const short8*)(p6 + kb + 512);
    short8 b71 = *(const short8*)(p7 + kb + 512);

    // ---- GEMM2(kc): 16 x 32x32x16 ----
    acc[0] = __builtin_amdgcn_mfma_f32_32x32x16_bf16(afA_c, b00, acc[0], 0, 0, 0);
    acc[1] = __builtin_amdgcn_mfma_f32_32x32x16_bf16(afA_c, b10, acc[1], 0, 0, 0);
    acc[2] = __builtin_amdgcn_mfma_f32_32x32x16_bf16(afA_c, b20, acc[2], 0, 0, 0);
    acc[3] = __builtin_amdgcn_mfma_f32_32x32x16_bf16(afA_c, b30, acc[3], 0, 0, 0);
    acc[4] = __builtin_amdgcn_mfma_f32_32x32x16_bf16(afA_c, b40, acc[4], 0, 0, 0);
    acc[5] = __builtin_amdgcn_mfma_f32_32x32x16_bf16(afA_c, b50, acc[5], 0, 0, 0);
    acc[6] = __builtin_amdgcn_mfma_f32_32x32x16_bf16(afA_c, b60, acc[6], 0, 0, 0);
    acc[7] = __builtin_amdgcn_mfma_f32_32x32x16_bf16(afA_c, b70, acc[7], 0, 0, 0);

    acc[0] = __builtin_amdgcn_mfma_f32_32x32x16_bf16(afB_c, b01, acc[0], 0, 0, 0);
    acc[1] = __builtin_amdgcn_mfma_f32_32x32x16_bf16(afB_c, b11, acc[1], 0, 0, 0);
    acc[2] = __builtin_amdgcn_mfma_f32_32x32x16_bf16(afB_c, b21, acc[2], 0, 0, 0);
    acc[3] = __builtin_amdgcn_mfma_f32_32x32x16_bf16(afB_c, b31, acc[3], 0, 0, 0);
    acc[4] = __builtin_amdgcn_mfma_f32_32x32x16_bf16(afB_c, b41, acc[4], 0, 0, 0);
    acc[5] = __builtin_amdgcn_mfma_f32_32x32x16_bf16(afB_c, b51, acc[5], 0, 0, 0);
    acc[6] = __builtin_amdgcn_mfma_f32_32x32x16_bf16(afB_c, b61, acc[6], 0, 0, 0);
    acc[7] = __builtin_amdgcn_mfma_f32_32x32x16_bf16(afB_c, b71, acc[7], 0, 0, 0);

    afA_c = afA_n;
    afB_c = afB_n;
  }

  // ---- epilogue: + b2, fp32 store ----
#pragma unroll
  for (int nt = 0; nt < 8; ++nt) {
    const int col = (nt0 + nt) * 32 + nl;
    const float bv = b2[col];
    const int rbase = tok0 + wave * 32 + 4 * hi;
#pragma unroll
    for (int g2 = 0; g2 < 4; ++g2)
#pragma unroll
      for (int rr = 0; rr < 4; ++rr)
        out[(size_t)(rbase + 8 * g2 + rr) * EMB + col] =
            acc[nt][4 * g2 + rr] + bv;
  }
}

extern "C" void kernel_launch(void* const* d_in, const int* in_sizes, int n_in,
                              void* d_out, int out_size, void* d_ws, size_t ws_size,
                              hipStream_t stream) {
  const float* x     = (const float*)d_in[0];
  const float* theta = (const float*)d_in[1];
  const float* W1    = (const float*)d_in[2];
  const float* b1    = (const float*)d_in[3];
  const float* W2    = (const float*)d_in[4];
  const float* b2    = (const float*)d_in[5];
  float* out = (float*)d_out;

  unsigned short* w1t = (unsigned short*)d_ws;       // FFN*16 = 32768 bf16
  unsigned short* w2f = w1t + FFN * 16;              // 1048576 bf16 (frag order)

  prep_all<<<dim3(FFN / 32, EMB / 32), 256, 0, stream>>>(W1, b1, W2, w1t, w2f);

  dim3 grid(T_TOK / BM, EMB / BN);  // (256, 2) = 512 blocks = 2/CU
  ffq_main<<<grid, 256, 0, stream>>>(x, theta, w1t, w2f, b2, out);
}

// Round 12
// 160.627 us; speedup vs baseline: 1.1391x; 1.1391x over previous
//
#include <hip/hip_runtime.h>

#define T_TOK 32768   // B*S
#define NQ    8
#define FFN   2048
#define EMB   512
#define BM    128
#define BN    256
#define BK    32
#define NCHUNK (FFN / BK)   // 64

typedef __attribute__((ext_vector_type(8)))  short short8;
typedef __attribute__((ext_vector_type(16))) float f32x16;
typedef __attribute__((ext_vector_type(2)))  unsigned int u32x2;

__device__ __forceinline__ unsigned short f2bf(float f) {
  unsigned int u = __float_as_uint(f);
  u += 0x7fffu + ((u >> 16) & 1u);
  return (unsigned short)(u >> 16);
}

__device__ __forceinline__ unsigned pk2bf(float lo, float hi) {
#if __has_builtin(__builtin_amdgcn_cvt_pk_bf16_f32)
  typedef __attribute__((ext_vector_type(2))) __bf16 bf2;
  bf2 p = __builtin_amdgcn_cvt_pk_bf16_f32(lo, hi);
  return *(unsigned*)&p;
#else
  return (unsigned)f2bf(lo) | ((unsigned)f2bf(hi) << 16);
#endif
}

// ---------------------------------------------------------------------------
// prep_all: W2[FFN][EMB] fp32 -> w2t[EMB][FFN] bf16 (tiled transpose), plus
//   w1t16[f][16]: k<8 = W1[k][f], k==8 = b1[f] (bias folded as extra input
//   row; main kernel's bq supplies 1.0 there), k>8 = 0.   (R10/R11-verified)
// ---------------------------------------------------------------------------
__global__ void prep_all(const float* __restrict__ W1,
                         const float* __restrict__ b1,
                         const float* __restrict__ W2,
                         unsigned short* __restrict__ w1t,
                         unsigned short* __restrict__ w2t) {
  __shared__ float t[32][33];
  const int kb = blockIdx.x * 32;   // FFN tile
  const int nb = blockIdx.y * 32;   // EMB tile
  const int tid = threadIdx.x;
  const int c = tid & 31, r0 = tid >> 5;
#pragma unroll
  for (int p = 0; p < 4; ++p) {
    int r = r0 + p * 8;
    t[r][c] = W2[(size_t)(kb + r) * EMB + nb + c];
  }
  __syncthreads();
#pragma unroll
  for (int p = 0; p < 4; ++p) {
    int r = r0 + p * 8;
    w2t[(size_t)(nb + r) * FFN + kb + c] = f2bf(t[c][r]);
  }
  if (blockIdx.x == 0) {
    const int f     = blockIdx.y * 128 + (tid >> 1);
    const int khalf = tid & 1;
    unsigned short v8[8];
#pragma unroll
    for (int j = 0; j < 8; ++j) {
      const int k = khalf * 8 + j;
      float val = (k < 8) ? W1[(size_t)k * FFN + f]
                          : (k == 8 ? b1[f] : 0.f);
      v8[j] = f2bf(val);
    }
    *(uint4*)(w1t + (size_t)f * 16 + khalf * 8) = *(uint4*)v8;
  }
}

// ---------------------------------------------------------------------------
// Fused main, R14: R11 + depth-3 software-pipelined ds_read rotation.
//   R13 diagnosis: acc=128 AGPR leaves ~16 arch-reg headroom at 2/SIMD ->
//   compiler can hoist only ~4 frags of LDS lookahead -> the 16 ds_read->
//   MFMA pairs run latency-exposed (~16 x 150cy ~= R11's period gap).
//   Fix (12 regs, fits headroom): three named rotating frag regs; each
//   MFMA's B-frag is loaded 3 MFMA-slots (~96cy) ahead; the 3-frag prefill
//   is covered by gemm1(nc) moved BEFORE the MFMA stream. Compiler emits
//   counted lgkmcnt (2 newer reads outstanding at each wait).
//   + setprio(1) around the MFMA stream (2 desynced blocks/CU = wave role
//   diversity; attn-positive regime).
//   Everything else identical to R11 (best = 83.4 us).
//   Spill tripwires: VGPR <= 128, WRITE_SIZE exactly 65536 KB.
// ---------------------------------------------------------------------------
__global__ __launch_bounds__(256, 2) void ffq_main(
    const float* __restrict__ x,
    const float* __restrict__ theta,
    const unsigned short* __restrict__ w1t,
    const unsigned short* __restrict__ w2t,
    const float* __restrict__ b2,
    float* __restrict__ out) {

  __shared__ __align__(16) unsigned short w2_lds[2][BN * BK];   // 32768 B

  const int tid  = threadIdx.x;
  const int wave = tid >> 6;
  const int lane = tid & 63;
  const int nl   = lane & 31;
  const int hi   = lane >> 5;
  const int tok0 = blockIdx.x * BM;
  const int n0   = blockIdx.y * BN;

  // ---- bq: B[k=q][tok]; hi half selects the bias row (k=8 -> 1.0) ----
  float cth[8];
  {
    const float4* tp = (const float4*)theta;
    float4 t0 = tp[0], t1 = tp[1];
    cth[0] = __cosf(t0.x); cth[1] = __cosf(t0.y);
    cth[2] = __cosf(t0.z); cth[3] = __cosf(t0.w);
    cth[4] = __cosf(t1.x); cth[5] = __cosf(t1.y);
    cth[6] = __cosf(t1.z); cth[7] = __cosf(t1.w);
  }
  short8 bq;
  {
    const float4* xp =
        (const float4*)(x + (size_t)(tok0 + wave * 32 + nl) * NQ);
    float4 x0 = xp[0], x1 = xp[1];
    float q0 = __cosf(x0.x) * cth[0], q1 = __cosf(x0.y) * cth[1];
    float q2 = __cosf(x0.z) * cth[2], q3 = __cosf(x0.w) * cth[3];
    float q4 = __cosf(x1.x) * cth[4], q5 = __cosf(x1.y) * cth[5];
    float q6 = __cosf(x1.z) * cth[6], q7 = __cosf(x1.w) * cth[7];
    uint4 uu;
    uu.x = pk2bf(q0, q1); uu.y = pk2bf(q2, q3);
    uu.z = pk2bf(q4, q5); uu.w = pk2bf(q6, q7);
    if (hi) { uu.x = 0x00003f80u; uu.y = 0; uu.z = 0; uu.w = 0; }  // k=8: 1.0
    bq = *(short8*)&uu;
  }

  // ---- w2 staging: linear LDS dest, pre-swizzled global source ----
  const int st_gc = (tid & 3) ^ ((tid >> 3) & 3);
  auto stage_w2 = [&](int kc_, int b_) {
    const int k0_ = kc_ * BK;
#pragma unroll
    for (int issue = 0; issue < 4; ++issue) {
      const int r = issue * 64 + (tid >> 2);
      __builtin_amdgcn_global_load_lds(
          (const __attribute__((address_space(1))) void*)(
              w2t + (size_t)(n0 + r) * FFN + k0_ + st_gc * 8),
          (__attribute__((address_space(3))) void*)(
              &w2_lds[b_][issue * 2048 + tid * 8]),
          16, 0, 0);
    }
  };

  // ---- GEMM2 B-frag read offsets (de-swizzle; col-tile-independent) ----
  const int swz  = (nl >> 1) & 3;
  const int off0 = nl * 32 + ((0 + hi) ^ swz) * 8;   // ks=0
  const int off1 = nl * 32 + ((2 + hi) ^ swz) * 8;   // ks=1

  f32x16 acc[8];
#pragma unroll
  for (int nt = 0; nt < 8; ++nt)
#pragma unroll
    for (int r = 0; r < 16; ++r) acc[nt][r] = 0.f;

  // ---- GEMM1 -> A-frags (R7/R10/R11-verified permlane routing) ----
  auto gemm1 = [&](short8 aw, short8& oA, short8& oB) {
    f32x16 c1;
#pragma unroll
    for (int r = 0; r < 16; ++r) c1[r] = 0.f;
    c1 = __builtin_amdgcn_mfma_f32_32x32x16_bf16(aw, bq, c1, 0, 0, 0);
    unsigned Q[8];
#pragma unroll
    for (int p = 0; p < 8; ++p) {
      float lo = c1[2 * p]     > 0.f ? c1[2 * p]     : 0.f;
      float hl = c1[2 * p + 1] > 0.f ? c1[2 * p + 1] : 0.f;
      Q[p] = pk2bf(lo, hl);
    }
    u32x2 s0 = __builtin_amdgcn_permlane32_swap(Q[0], Q[2], false, false);
    u32x2 s1 = __builtin_amdgcn_permlane32_swap(Q[1], Q[3], false, false);
    u32x2 s2 = __builtin_amdgcn_permlane32_swap(Q[4], Q[6], false, false);
    u32x2 s3 = __builtin_amdgcn_permlane32_swap(Q[5], Q[7], false, false);
    uint4 uA; uA.x = s0[0]; uA.y = s1[0]; uA.z = s0[1]; uA.w = s1[1];
    uint4 uB; uB.x = s2[0]; uB.y = s3[0]; uB.z = s2[1]; uB.w = s3[1];
    oA = *(short8*)&uA;
    oB = *(short8*)&uB;
  };

  // ---- prologue: stage chunk 0; GEMM1(0) while the stage flies ----
  short8 afA_c, afB_c, afA_n, afB_n;
  {
    stage_w2(0, 0);
    short8 aw0 = *(const short8*)(w1t + (size_t)nl * 16 + hi * 8);
    gemm1(aw0, afA_c, afB_c);
  }

#define MF(a, b, c) __builtin_amdgcn_mfma_f32_32x32x16_bf16((a), (b), (c), 0, 0, 0)

#pragma unroll 2
  for (int kc = 0; kc < NCHUNK; ++kc) {
    const int b  = kc & 1;
    const int nc = (kc + 1 < NCHUNK) ? kc + 1 : NCHUNK - 1;  // clamp: uniform

    // stage(kc) had a full chunk of compute to land -> near-free drain
    asm volatile("s_waitcnt vmcnt(0)" ::: "memory");
    __builtin_amdgcn_s_barrier();   // w2[b] ready; readers of w2[b^1] done
    __builtin_amdgcn_sched_barrier(0);

    // aw for GEMM1(nc)
    short8 aw = *(const short8*)(w1t + (size_t)(nc * BK + nl) * 16 + hi * 8);

    stage_w2(nc, b ^ 1);            // prefetch next chunk (stays in flight)

    const unsigned short* sb = &w2_lds[b][0];
    auto LDA = [&](int t) { return *(const short8*)(sb + off0 + t * 1024); };
    auto LDB = [&](int t) { return *(const short8*)(sb + off1 + t * 1024); };

    // ---- prefill 3 frags; gemm1(nc) covers their ds latency ----
    short8 ra = LDA(0), rb = LDA(1), rc = LDA(2);
    gemm1(aw, afA_n, afB_n);

    // ---- GEMM2(kc): 16-step stream, depth-3 rotating B-frag pipeline ----
    __builtin_amdgcn_s_setprio(1);
    acc[0] = MF(afA_c, ra, acc[0]);  ra = LDA(3);
    acc[1] = MF(afA_c, rb, acc[1]);  rb = LDA(4);
    acc[2] = MF(afA_c, rc, acc[2]);  rc = LDA(5);
    acc[3] = MF(afA_c, ra, acc[3]);  ra = LDA(6);
    acc[4] = MF(afA_c, rb, acc[4]);  rb = LDA(7);
    acc[5] = MF(afA_c, rc, acc[5]);  rc = LDB(0);
    acc[6] = MF(afA_c, ra, acc[6]);  ra = LDB(1);
    acc[7] = MF(afA_c, rb, acc[7]);  rb = LDB(2);
    acc[0] = MF(afB_c, rc, acc[0]);  rc = LDB(3);
    acc[1] = MF(afB_c, ra, acc[1]);  ra = LDB(4);
    acc[2] = MF(afB_c, rb, acc[2]);  rb = LDB(5);
    acc[3] = MF(afB_c, rc, acc[3]);  rc = LDB(6);
    acc[4] = MF(afB_c, ra, acc[4]);  ra = LDB(7);
    acc[5] = MF(afB_c, rb, acc[5]);
    acc[6] = MF(afB_c, rc, acc[6]);
    acc[7] = MF(afB_c, ra, acc[7]);
    __builtin_amdgcn_s_setprio(0);

    afA_c = afA_n;
    afB_c = afB_n;
  }
#undef MF

  // drain the clamped last prefetch before LDS goes away
  asm volatile("s_waitcnt vmcnt(0)" ::: "memory");

  // ---- epilogue: + b2, fp32 store ----
#pragma unroll
  for (int nt = 0; nt < 8; ++nt) {
    const int col = n0 + nt * 32 + nl;
    const float bv = b2[col];
    const int rbase = tok0 + wave * 32 + 4 * hi;
#pragma unroll
    for (int g2 = 0; g2 < 4; ++g2)
#pragma unroll
      for (int rr = 0; rr < 4; ++rr)
        out[(size_t)(rbase + 8 * g2 + rr) * EMB + col] =
            acc[nt][4 * g2 + rr] + bv;
  }
}

extern "C" void kernel_launch(void* const* d_in, const int* in_sizes, int n_in,
                              void* d_out, int out_size, void* d_ws, size_t ws_size,
                              hipStream_t stream) {
  const float* x     = (const float*)d_in[0];
  const float* theta = (const float*)d_in[1];
  const float* W1    = (const float*)d_in[2];
  const float* b1    = (const float*)d_in[3];
  const float* W2    = (const float*)d_in[4];
  const float* b2    = (const float*)d_in[5];
  float* out = (float*)d_out;

  unsigned short* w1t = (unsigned short*)d_ws;       // FFN*16 = 32768 bf16
  unsigned short* w2t = w1t + FFN * 16;              // 1048576 bf16 [EMB][FFN]

  prep_all<<<dim3(FFN / 32, EMB / 32), 256, 0, stream>>>(W1, b1, W2, w1t, w2t);

  dim3 grid(T_TOK / BM, EMB / BN);  // (256, 2) = 512 blocks = 2/CU
  ffq_main<<<grid, 256, 0, stream>>>(x, theta, w1t, w2t, b2, out);
}